// Round 9
// baseline (110.463 us; speedup 1.0000x reference)
//
#include <hip/hip_runtime.h>
#include <hip/hip_fp16.h>

#define CCH 128
#define SV 24
#define NVOX 13824   // 24^3

typedef unsigned short u16;
typedef unsigned int   u32;

// unpack uint4 (8 packed fp16) -> 8 floats
__device__ __forceinline__ void cvt8h(uint4 r, float* f) {
    const __half2* h = (const __half2*)&r;
    const float2 a = __half22float2(h[0]);
    const float2 b = __half22float2(h[1]);
    const float2 c = __half22float2(h[2]);
    const float2 d = __half22float2(h[3]);
    f[0] = a.x; f[1] = a.y; f[2] = b.x; f[3] = b.y;
    f[4] = c.x; f[5] = c.y; f[6] = d.x; f[7] = d.y;
}
__device__ __forceinline__ u32 pack2h(float a, float b) {
    const __half2 h = __floats2half2_rn(a, b);
    return *(const u32*)&h;
}

// ---------------------------------------------------------------------------
// Projection GEMM: C[vox][o] = sum_c X[c][vox] * W[o][c] + b[o].
// One m in {q,k,v} per blockIdx.y. Block = 64 vox x 128 o, K-tile 32.
// XCD swizzle: dispatch maps block (bx + by*216) -> XCD (bx%8) since
// 216 % 8 == 0; we assign vox slab = bx%8 so XCD x produces q/k/v for the
// contiguous vox range [x*1728, (x+1)*1728) -> its own L2 (1.5 MB k+v).
// q -> d_out fp32; k/v -> ws packed fp16 + pad row (= bias) at NVOX.
// Grid (216, 3).
// ---------------------------------------------------------------------------
__global__ __launch_bounds__(256) void proj_kernel(
    const float* __restrict__ x,
    const float* __restrict__ wq, const float* __restrict__ bq,
    const float* __restrict__ wk, const float* __restrict__ bk,
    const float* __restrict__ wv, const float* __restrict__ bv,
    const float* __restrict__ relh, const float* __restrict__ relw,
    const float* __restrict__ reld,
    float* __restrict__ qout, u16* __restrict__ kws, u16* __restrict__ vws,
    float* __restrict__ biasW)
{
    const int m = blockIdx.y;                  // 0=q 1=k 2=v
    const float* __restrict__ w = (m == 0) ? wq : (m == 1) ? wk : wv;
    const float* __restrict__ b = (m == 0) ? bq : (m == 1) ? bk : bv;

    __shared__ float Xs[32][64];
    __shared__ float Ws[32][128];

    const int tid  = threadIdx.x;
    const int bx   = blockIdx.x;
    // XCD-affinity swizzle: slab = bx%8 (the XCD this block lands on)
    const int vox0 = (((bx & 7) * 27) + (bx >> 3)) * 64;
    const int v0   = (tid & 15) * 4;           // compute: voxel group
    const int o0   = (tid >> 4) * 8;           // compute: output group

    // staging indices
    const int xc  = tid >> 3;                  // 0..31  (c-row)
    const int xv  = (tid & 7) * 4;             // 0,4,..,28
    const int wo  = tid >> 1;                  // 0..127 (o-row)
    const int wkh = (tid & 1) * 16;            // 0 or 16

    float acc[4][8] = {{0.f}};

    for (int k0 = 0; k0 < CCH; k0 += 32) {
        // X slice: 32 c-rows x 64 vox, coalesced (8 lanes cover 256B row)
        {
            const float* src = x + (size_t)(k0 + xc) * NVOX + vox0 + xv;
            const float4 a0 = *(const float4*)src;
            const float4 a1 = *(const float4*)(src + 32);
            *(float4*)&Xs[xc][xv]      = a0;
            *(float4*)&Xs[xc][xv + 32] = a1;
        }
        // W slice: rows [o][k0+wkh .. +15] -> transposed Ws[k][o]
        {
            const float* src = w + (size_t)wo * CCH + k0 + wkh;
            const float4 b0 = *(const float4*)src;
            const float4 b1 = *(const float4*)(src + 4);
            const float4 b2 = *(const float4*)(src + 8);
            const float4 b3 = *(const float4*)(src + 12);
            Ws[wkh + 0][wo] = b0.x;  Ws[wkh + 1][wo] = b0.y;
            Ws[wkh + 2][wo] = b0.z;  Ws[wkh + 3][wo] = b0.w;
            Ws[wkh + 4][wo] = b1.x;  Ws[wkh + 5][wo] = b1.y;
            Ws[wkh + 6][wo] = b1.z;  Ws[wkh + 7][wo] = b1.w;
            Ws[wkh + 8][wo] = b2.x;  Ws[wkh + 9][wo] = b2.y;
            Ws[wkh + 10][wo] = b2.z; Ws[wkh + 11][wo] = b2.w;
            Ws[wkh + 12][wo] = b3.x; Ws[wkh + 13][wo] = b3.y;
            Ws[wkh + 14][wo] = b3.z; Ws[wkh + 15][wo] = b3.w;
        }
        __syncthreads();

#pragma unroll
        for (int k = 0; k < 32; ++k) {
            const float4 xf = *(const float4*)&Xs[k][v0];
            const float4 w0 = *(const float4*)&Ws[k][o0];
            const float4 w1 = *(const float4*)&Ws[k][o0 + 4];
            const float xr[4] = {xf.x, xf.y, xf.z, xf.w};
            const float wr[8] = {w0.x, w0.y, w0.z, w0.w,
                                 w1.x, w1.y, w1.z, w1.w};
#pragma unroll
            for (int vv = 0; vv < 4; ++vv)
#pragma unroll
                for (int oo = 0; oo < 8; ++oo)
                    acc[vv][oo] = fmaf(xr[vv], wr[oo], acc[vv][oo]);
        }
        __syncthreads();
    }

    const float4 bf0 = *(const float4*)(b + o0);
    const float4 bf1 = *(const float4*)(b + o0 + 4);
    const float br[8] = {bf0.x, bf0.y, bf0.z, bf0.w,
                         bf1.x, bf1.y, bf1.z, bf1.w};

#pragma unroll
    for (int vv = 0; vv < 4; ++vv) {
        float r[8];
#pragma unroll
        for (int oo = 0; oo < 8; ++oo) r[oo] = acc[vv][oo] + br[oo];
        const size_t row = (size_t)(vox0 + v0 + vv) * CCH + o0;
        if (m == 0) {
            float4 s0 = {r[0], r[1], r[2], r[3]};
            float4 s1 = {r[4], r[5], r[6], r[7]};
            *(float4*)(qout + row) = s0;
            *(float4*)(qout + row + 4) = s1;
        } else {
            u16* out = (m == 1) ? kws : vws;
            uint4 st = {pack2h(r[0], r[1]), pack2h(r[2], r[3]),
                        pack2h(r[4], r[5]), pack2h(r[6], r[7])};
            *(uint4*)(out + row) = st;
        }
    }

    if (blockIdx.x == 0) {
        if (m == 1 && tid < CCH) {
            const __half hb = __float2half_rn(bk[tid]);
            kws[(size_t)NVOX * CCH + tid] = *(const u16*)&hb;
        }
        if (m == 2 && tid < CCH) {
            const __half hb = __float2half_rn(bv[tid]);
            vws[(size_t)NVOX * CCH + tid] = *(const u16*)&hb;
        }
        if (m == 1 && tid < 27) {
            const int i = tid / 9, j = (tid / 3) % 3, l = tid % 3;
            float s = 0.f;
            for (int c = 0; c < 64; ++c)
                s += relh[c * 3 + i] + relw[c * 3 + j] + reld[c * 3 + l];
            biasW[tid] = s;
        }
    }
}

// ---------------------------------------------------------------------------
// neighbor row offset for window slot s (folds at compile time after unroll)
// ---------------------------------------------------------------------------
__device__ __forceinline__ int nbr_off(int h, int w, int d, int s, int ch) {
    const int nh = h + s / 9 - 1;
    const int nw = w + (s / 3) % 3 - 1;
    const int nd = d + s % 3 - 1;
    const bool ok = ((unsigned)nh < (unsigned)SV) &&
                    ((unsigned)nw < (unsigned)SV) &&
                    ((unsigned)nd < (unsigned)SV);
    const int idx = ok ? ((nh * SV + nw) * SV + nd) : NVOX;
    return idx * CCH + ch;
}

// ---------------------------------------------------------------------------
// Attention: 16 lanes/voxel (8 ch each), 16 voxels per 256-thr block.
// XCD swizzle: slab = blockIdx%8 matches proj's producer slab, so the k/v
// rows this block gathers were written into THIS XCD's L2 (halo ~17% misses
// to L3). q fp32 from d_out, overwritten in place. Grid 864.
// ---------------------------------------------------------------------------
__global__ __launch_bounds__(256) void attn_kernel(
    float* __restrict__ qo, const u16* __restrict__ kws,
    const u16* __restrict__ vws, const float* __restrict__ biasW)
{
    const int tid  = threadIdx.x;
    const int lane = tid & 15;
    const int bx   = blockIdx.x;
    const int vox  = (((bx & 7) * 108) + (bx >> 3)) * 16 + (tid >> 4);
    const int h    = vox / 576;
    const int rem  = vox - h * 576;
    const int w    = rem / 24;
    const int d    = rem - w * 24;
    const int ch   = lane * 8;

    const float* qrow = qo + (size_t)vox * CCH + ch;
    const float4 q0 = *(const float4*)qrow;
    const float4 q1 = *(const float4*)(qrow + 4);
    const float qr[8] = {q0.x, q0.y, q0.z, q0.w, q1.x, q1.y, q1.z, q1.w};

    float qs = qr[0] + qr[1] + qr[2] + qr[3] + qr[4] + qr[5] + qr[6] + qr[7];
#pragma unroll
    for (int mm = 1; mm < 16; mm <<= 1) qs += __shfl_xor(qs, mm, 64);

    float ps[27];
    // ---- QK phase: 3 batches of 9 rows ----
#pragma unroll
    for (int sb = 0; sb < 27; sb += 9) {
        uint4 kf[9];
#pragma unroll
        for (int j = 0; j < 9; ++j)
            kf[j] = *(const uint4*)(kws + nbr_off(h, w, d, sb + j, ch));
#pragma unroll
        for (int j = 0; j < 9; ++j) {
            float f[8];
            cvt8h(kf[j], f);
            float p = qr[0] * f[0];
            p = fmaf(qr[1], f[1], p); p = fmaf(qr[2], f[2], p);
            p = fmaf(qr[3], f[3], p); p = fmaf(qr[4], f[4], p);
            p = fmaf(qr[5], f[5], p); p = fmaf(qr[6], f[6], p);
            p = fmaf(qr[7], f[7], p);
            ps[sb + j] = p;
        }
    }

#pragma unroll
    for (int mm = 1; mm < 16; mm <<= 1) {
#pragma unroll
        for (int s = 0; s < 27; ++s) ps[s] += __shfl_xor(ps[s], mm, 64);
    }

#pragma unroll
    for (int s = 0; s < 27; ++s) ps[s] = fmaf(qs, biasW[s], ps[s]);

    float mx = ps[0];
#pragma unroll
    for (int s = 1; s < 27; ++s) mx = fmaxf(mx, ps[s]);
    float sum = 0.f;
#pragma unroll
    for (int s = 0; s < 27; ++s) { ps[s] = __expf(ps[s] - mx); sum += ps[s]; }
    const float inv = 1.f / sum;
#pragma unroll
    for (int s = 0; s < 27; ++s) ps[s] *= inv;

    // ---- PV phase: 3 batches of 9 rows ----
    float o[8] = {0.f, 0.f, 0.f, 0.f, 0.f, 0.f, 0.f, 0.f};
#pragma unroll
    for (int sb = 0; sb < 27; sb += 9) {
        uint4 vf[9];
#pragma unroll
        for (int j = 0; j < 9; ++j)
            vf[j] = *(const uint4*)(vws + nbr_off(h, w, d, sb + j, ch));
#pragma unroll
        for (int j = 0; j < 9; ++j) {
            float f[8];
            cvt8h(vf[j], f);
            const float a = ps[sb + j];
#pragma unroll
            for (int e = 0; e < 8; ++e) o[e] = fmaf(a, f[e], o[e]);
        }
    }

    float* dst = qo + (size_t)vox * CCH + ch;
    float4 s0 = {o[0], o[1], o[2], o[3]};
    float4 s1 = {o[4], o[5], o[6], o[7]};
    *(float4*)dst = s0;
    *(float4*)(dst + 4) = s1;
}

// ---------------------------------------------------------------------------
extern "C" void kernel_launch(void* const* d_in, const int* in_sizes, int n_in,
                              void* d_out, int out_size, void* d_ws,
                              size_t ws_size, hipStream_t stream)
{
    const float* x    = (const float*)d_in[0];
    const float* wq   = (const float*)d_in[1];
    const float* bq   = (const float*)d_in[2];
    const float* wk   = (const float*)d_in[3];
    const float* bk   = (const float*)d_in[4];
    const float* wv   = (const float*)d_in[5];
    const float* bv   = (const float*)d_in[6];
    const float* relh = (const float*)d_in[7];
    const float* relw = (const float*)d_in[8];
    const float* reld = (const float*)d_in[9];

    u16*   kws   = (u16*)d_ws;                         // (NVOX+1)*128 fp16
    u16*   vws   = kws + (size_t)(NVOX + 1) * CCH;     // (NVOX+1)*128 fp16
    float* biasW = (float*)(vws + (size_t)(NVOX + 1) * CCH);  // 27 fp32

    dim3 pgrid(NVOX / 64, 3);
    proj_kernel<<<pgrid, 256, 0, stream>>>(x, wq, bq, wk, bk, wv, bv,
                                           relh, relw, reld,
                                           (float*)d_out, kws, vws, biasW);
    attn_kernel<<<NVOX / 16, 256, 0, stream>>>((float*)d_out, kws, vws, biasW);
}